// Round 4
// baseline (258.809 us; speedup 1.0000x reference)
//
#include <hip/hip_runtime.h>

#define DEV __device__ __forceinline__

// ---------------------------------------------------------------------------
// B-spline machinery: GRID_SIZE=5, DEGREE=3, knots t_i = (i-3)*0.4 - 1.
// Cox-de Boor exactly as the reference. All-unrolled, no runtime indexing.
// ---------------------------------------------------------------------------
DEV float silu_f(float v) { return v / (1.0f + __expf(-v)); }

DEV void bspline8(float x, float bb[8]) {
    float b[11];
#pragma unroll
    for (int i = 0; i < 11; ++i) {
        float g0 = (i - 3) * 0.4f - 1.0f;
        float g1 = (i - 2) * 0.4f - 1.0f;
        b[i] = ((x >= g0) && (x < g1)) ? 1.0f : 0.0f;
    }
#pragma unroll
    for (int d = 1; d <= 3; ++d) {
        const float inv = 1.0f / (0.4f * (float)d);
#pragma unroll
        for (int i = 0; i < 11 - d; ++i) {
            float gl = (i - 3) * 0.4f - 1.0f;
            float gr = (i - 3 + d + 1) * 0.4f - 1.0f;
            b[i] = (x - gl) * inv * b[i] + (gr - x) * inv * b[i + 1];
        }
    }
#pragma unroll
    for (int j = 0; j < 8; ++j) bb[j] = b[j];
}

// bf16 RNE pack/unpack (bases are bounded, no inf/nan concerns).
DEV unsigned bf16rne(float x) {
    unsigned u = __float_as_uint(x);
    u += 0x7fffu + ((u >> 16) & 1u);
    return u >> 16;
}
DEV uint4 pack8(const float bb[8]) {
    uint4 q;
    q.x = bf16rne(bb[0]) | (bf16rne(bb[1]) << 16);
    q.y = bf16rne(bb[2]) | (bf16rne(bb[3]) << 16);
    q.z = bf16rne(bb[4]) | (bf16rne(bb[5]) << 16);
    q.w = bf16rne(bb[6]) | (bf16rne(bb[7]) << 16);
    return q;
}
DEV void unpack8(uint4 q, float f[8]) {
    f[0] = __uint_as_float(q.x << 16);
    f[1] = __uint_as_float(q.x & 0xffff0000u);
    f[2] = __uint_as_float(q.y << 16);
    f[3] = __uint_as_float(q.y & 0xffff0000u);
    f[4] = __uint_as_float(q.z << 16);
    f[5] = __uint_as_float(q.z & 0xffff0000u);
    f[6] = __uint_as_float(q.w << 16);
    f[7] = __uint_as_float(q.w & 0xffff0000u);
}

// Even/odd-x column permutation: even x -> x/2, odd x -> W/2 + x/2.
// Makes the pooled conv's stride-2-x gathers stride-1 (conflict-free).
template <int W, bool PERM>
DEV int permcol(int x) {
    if (!PERM) return x;
    return (x & 1) ? (W / 2 + (x >> 1)) : (x >> 1);
}

// ---------------------------------------------------------------------------
// Expansion: silu (f32) + 8 bases (bf16x8 in one uint4) per input element.
// Reads src linearly, writes at the (optionally) column-permuted index.
// Element NE is the zero-pad element: sil=0, bases=B(0).
// ---------------------------------------------------------------------------
template <int W, bool PERM>
DEV void expand_feat(const float* src, int NE, float* s_sil, uint4* s_bs, int tid) {
    for (int i = tid; i <= NE; i += 256) {
        float v = (i == NE) ? 0.0f : src[i];
        float bb[8];
        bspline8(v, bb);
        int widx = i;
        if (i < NE) {
            int y = i / W;
            int x = i - y * W;
            widx = y * W + permcol<W, PERM>(x);
        }
        s_sil[widx] = (i == NE) ? 0.0f : silu_f(v);
        s_bs[widx] = pack8(bb);
    }
}

// ---------------------------------------------------------------------------
// Fused KANConv (k=3,pad=1) + 2x2/2 maxpool, pool done in registers.
// Each lane owns a 2x2 output patch for G channels. The 4x4 input support is
// read once per (c,position). Weights via wave-uniform indices -> s_load.
// ---------------------------------------------------------------------------
template <int CIN, int H, int W, int O, int G, bool PERM>
DEV void conv_pool_phase(const float* __restrict__ wb, const float* __restrict__ ws,
                         const float* s_sil, const uint4* s_bs, float* dst, int tid) {
    constexpr int PH = H / 2;
    constexpr int HW2 = W / 2;
    constexpr int NPATCH = PH * PH;
    constexpr int NPIX = H * W;
    constexpr int NIN = CIN * NPIX;
    constexpr int F = CIN * 9;
    constexpr int NOG = O / G;
    static_assert(4 % NOG == 0, "waves must cover groups");

    const int wv = __builtin_amdgcn_readfirstlane(tid >> 6);
    const int ln = tid & 63;
    const int og = wv % NOG;            // uniform per wave
    const int poff = (wv / NOG) * 64;   // uniform per wave
    constexpr int PSTRIDE = 64 * (4 / NOG);

    for (int p = ln + poff; p < NPATCH; p += PSTRIDE) {
        const int py = p / PH, px = p - py * PH;
        int rowb[4], colb[4];
#pragma unroll
        for (int u = 0; u < 4; ++u) {
            int iy = 2 * py + u - 1;
            rowb[u] = ((unsigned)iy < (unsigned)H) ? iy * W : -0x40000000;
        }
#pragma unroll
        for (int v = 0; v < 4; ++v) {
            int ix = 2 * px + v - 1;
            int pc;
            if (PERM)
                pc = (v == 0) ? (HW2 + px - 1)
                              : (v == 1) ? px : (v == 2) ? (HW2 + px) : (px + 1);
            else
                pc = ix;
            colb[v] = ((unsigned)ix < (unsigned)W) ? pc : -0x40000000;
        }
        float acc[G][4];
#pragma unroll
        for (int g = 0; g < G; ++g)
#pragma unroll
            for (int q = 0; q < 4; ++q) acc[g][q] = 0.0f;

#pragma unroll 1
        for (int c = 0; c < CIN; ++c) {
#pragma unroll
            for (int u = 0; u < 4; ++u) {
#pragma unroll
                for (int v = 0; v < 4; ++v) {
                    const int raw = rowb[u] + colb[v];
                    const int idx = (raw < 0) ? NIN : c * NPIX + raw;
                    const float s = s_sil[idx];
                    float f[8];
                    unpack8(s_bs[idx], f);
#pragma unroll
                    for (int oy = 0; oy < 2; ++oy) {
                        const int dy = u - oy;
                        if (dy < 0 || dy > 2) continue;
#pragma unroll
                        for (int ox = 0; ox < 2; ++ox) {
                            const int dx = v - ox;
                            if (dx < 0 || dx > 2) continue;
                            const int ff = c * 9 + dy * 3 + dx;
#pragma unroll
                            for (int g = 0; g < G; ++g) {
                                const int o = og * G + g;                  // uniform
                                const float* w8 = ws + (o * F + ff) * 8;   // -> s_load
                                float ag = acc[g][oy * 2 + ox];
                                ag = fmaf(wb[o * F + ff], s, ag);
#pragma unroll
                                for (int j = 0; j < 8; ++j) ag = fmaf(w8[j], f[j], ag);
                                acc[g][oy * 2 + ox] = ag;
                            }
                        }
                    }
                }
            }
        }
#pragma unroll
        for (int g = 0; g < G; ++g) {
            float m = fmaxf(fmaxf(acc[g][0], acc[g][1]), fmaxf(acc[g][2], acc[g][3]));
            dst[(og * G + g) * NPATCH + p] = m;
        }
    }
}

// ---------------------------------------------------------------------------
// Pixel-wise KANConv (odd 7x7 layer, no perm), writes conv output to s_out.
// ---------------------------------------------------------------------------
template <int CIN, int H, int W, int O, int G>
DEV void conv_phase(const float* __restrict__ wb, const float* __restrict__ ws,
                    const float* s_sil, const uint4* s_bs, float* s_out, int tid) {
    constexpr int NPIX = H * W;
    constexpr int F = CIN * 9;
    constexpr int NOG = O / G;
    constexpr int NIN = CIN * NPIX;
    static_assert(4 % NOG == 0, "waves must cover groups");

    const int wv = __builtin_amdgcn_readfirstlane(tid >> 6);
    const int ln = tid & 63;
    const int og = wv % NOG;
    const int pxoff = (wv / NOG) * 64;
    constexpr int PXSTRIDE = 64 * (4 / NOG);

    for (int px = ln + pxoff; px < NPIX; px += PXSTRIDE) {
        const int y = px / W, x = px - y * W;
        int rowb[3], colb[3];
#pragma unroll
        for (int t = 0; t < 3; ++t) {
            int iy = y + t - 1;
            rowb[t] = ((unsigned)iy < (unsigned)H) ? iy * W : -0x40000000;
            int ix = x + t - 1;
            colb[t] = ((unsigned)ix < (unsigned)W) ? ix : -0x40000000;
        }
        float acc[G];
#pragma unroll
        for (int g = 0; g < G; ++g) acc[g] = 0.0f;

#pragma unroll 1
        for (int c = 0; c < CIN; ++c) {
#pragma unroll
            for (int ty = 0; ty < 3; ++ty) {
#pragma unroll
                for (int tx = 0; tx < 3; ++tx) {
                    const int raw = rowb[ty] + colb[tx];
                    const int idx = (raw < 0) ? NIN : c * NPIX + raw;
                    const float s = s_sil[idx];
                    float f[8];
                    unpack8(s_bs[idx], f);
                    const int ff = c * 9 + ty * 3 + tx;
#pragma unroll
                    for (int g = 0; g < G; ++g) {
                        const int o = og * G + g;
                        const float* w8 = ws + (o * F + ff) * 8;
                        float ag = acc[g];
                        ag = fmaf(wb[o * F + ff], s, ag);
#pragma unroll
                        for (int j = 0; j < 8; ++j) ag = fmaf(w8[j], f[j], ag);
                        acc[g] = ag;
                    }
                }
            }
        }
#pragma unroll
        for (int g = 0; g < G; ++g) s_out[(og * G + g) * NPIX + px] = acc[g];
    }
}

// ---------------------------------------------------------------------------
// Layer-4 weight pre-reduction (sample independent, one tiny launch).
// wr layout: [0,512) Wb~[32][16]; [512,4608) Ws~[32][16][8]; [4608,4640) beta7
// ---------------------------------------------------------------------------
__global__ __launch_bounds__(256) void kan4_reduce(const float* __restrict__ wb4,
                                                   const float* __restrict__ ws4,
                                                   float* __restrict__ wr) {
    const int tid = threadIdx.x;
    for (int i = tid; i < 32 * 16; i += 256) {
        int o = i / 16, c = i % 16;
        float s = 0.0f;
        for (int q = 0; q < 4; ++q) s += wb4[o * 64 + c * 4 + q];
        wr[i] = s;
    }
    for (int i = tid; i < 32 * 16 * 8; i += 256) {
        int j = i % 8, c = (i / 8) % 16, o = i / 128;
        float s = 0.0f;
        for (int q = 0; q < 4; ++q) s += ws4[(o * 64 + c * 4 + q) * 8 + j];
        wr[512 + i] = s;
    }
    float zbb[8];
    bspline8(0.0f, zbb);
    for (int o = tid; o < 32; o += 256) {
        float s = 0.0f;
        for (int f = 0; f < 64; ++f)
#pragma unroll
            for (int j = 0; j < 8; ++j) s += ws4[(o * 64 + f) * 8 + j] * zbb[j];
        wr[512 + 4096 + o] = 7.0f * s;
    }
}

// ---------------------------------------------------------------------------
// Fully fused network: one block per sample, ~19.5 KB LDS -> 8 blocks/CU.
// ---------------------------------------------------------------------------
__global__ __launch_bounds__(256, 8) void kan_fused(
    const float* __restrict__ x,
    const float* __restrict__ wb1, const float* __restrict__ ws1,
    const float* __restrict__ wb2, const float* __restrict__ ws2,
    const float* __restrict__ wb3, const float* __restrict__ ws3,
    const float* __restrict__ wr, const float* __restrict__ fcw,
    const float* __restrict__ fcb, float* __restrict__ out) {
    __shared__ float s_sil[785];
    __shared__ uint4 s_bs[785];   // 8 bf16 bases per element
    __shared__ float s_p[784];
    __shared__ float s_cs[144];
    __shared__ float s_pool[32];

    const int b = blockIdx.x;
    const int tid = threadIdx.x;

    for (int i = tid; i < 784; i += 256) s_p[i] = x[(size_t)b * 784 + i];
    __syncthreads();

    // ----- layer 1: [1,28,28] -> conv+pool -> [4,14,14] (in s_p)
    expand_feat<28, true>(s_p, 784, s_sil, s_bs, tid);
    __syncthreads();
    conv_pool_phase<1, 28, 28, 4, 2, true>(wb1, ws1, s_sil, s_bs, s_p, tid);
    __syncthreads();

    // ----- layer 2: [4,14,14] -> conv+pool -> [8,7,7] (in s_p)
    expand_feat<14, true>(s_p, 784, s_sil, s_bs, tid);
    __syncthreads();
    conv_pool_phase<4, 14, 14, 8, 2, true>(wb2, ws2, s_sil, s_bs, s_p, tid);
    __syncthreads();

    // ----- layer 3: [8,7,7] -> conv [16,7,7] (into s_p) -> pool [16,3,3] (s_cs)
    expand_feat<7, false>(s_p, 392, s_sil, s_bs, tid);
    __syncthreads();
    conv_phase<8, 7, 7, 16, 4>(wb3, ws3, s_sil, s_bs, s_p, tid);
    __syncthreads();
    for (int i = tid; i < 144; i += 256) {
        int o = i / 9;
        int r = i - o * 9;
        int py = r / 3, qx = r - py * 3;
        const float* src = &s_p[o * 49 + (2 * py) * 7 + 2 * qx];
        s_cs[i] = fmaxf(fmaxf(src[0], src[1]), fmaxf(src[7], src[8]));
    }
    __syncthreads();

    // ----- layer 4 + global-avg + fc (algebraically collapsed via wr)
    // Planar f32 scratch aliasing s_bs: s_exp[e*9 + comp], comp 0 = silu,
    // comp 1+j = basis j. No runtime-indexed private arrays anywhere.
    float* s_exp = (float*)s_bs;  // needs 144*9 = 1296 floats (s_bs has 3140)
    if (tid < 144) {
        float v = s_cs[tid];
        float bb[8];
        bspline8(v, bb);
        s_exp[tid * 9 + 0] = silu_f(v);
#pragma unroll
        for (int j = 0; j < 8; ++j) s_exp[tid * 9 + 1 + j] = bb[j];
    }
    __syncthreads();
    if (tid < 144) {  // 16 channels x 9 components, summed over 9 pixels
        int c = tid / 9, comp = tid - (tid / 9) * 9;
        float s = 0.0f;
#pragma unroll
        for (int p = 0; p < 9; ++p) s += s_exp[(c * 9 + p) * 9 + comp];
        s_sil[tid] = s;  // channel-component sums
    }
    __syncthreads();
    if (tid < 32) {
        int o = tid;
        float acc = wr[4608 + o];  // 7 * sum(ws4 * B(0))
        for (int c = 0; c < 16; ++c) {
            acc += wr[o * 16 + c] * s_sil[c * 9 + 0];
#pragma unroll
            for (int j = 0; j < 8; ++j)
                acc += wr[512 + (o * 16 + c) * 8 + j] * s_sil[c * 9 + 1 + j];
        }
        s_pool[o] = acc * (1.0f / 16.0f);
    }
    __syncthreads();
    if (tid < 10) {
        float acc = fcb[tid];
#pragma unroll
        for (int c = 0; c < 32; ++c) acc += fcw[tid * 32 + c] * s_pool[c];
        out[(size_t)b * 10 + tid] = acc;
    }
}

// ---------------------------------------------------------------------------
extern "C" void kernel_launch(void* const* d_in, const int* in_sizes, int n_in,
                              void* d_out, int out_size, void* d_ws, size_t ws_size,
                              hipStream_t stream) {
    const float* x = (const float*)d_in[0];      // [B,1,28,28]
    const float* wb1 = (const float*)d_in[1];    // [4,9]
    const float* ws1 = (const float*)d_in[2];    // [4,9,8]
    const float* wb2 = (const float*)d_in[3];    // [8,36]
    const float* ws2 = (const float*)d_in[4];    // [8,36,8]
    const float* wb3 = (const float*)d_in[5];    // [16,72]
    const float* ws3 = (const float*)d_in[6];    // [16,72,8]
    const float* wb4 = (const float*)d_in[7];    // [32,64]
    const float* ws4 = (const float*)d_in[8];    // [32,64,8]
    const float* fcw = (const float*)d_in[9];    // [10,32]
    const float* fcb = (const float*)d_in[10];   // [10]
    float* out = (float*)d_out;

    const int B = in_sizes[0] / (28 * 28);
    float* wr = (float*)d_ws;  // 4640 floats

    kan4_reduce<<<1, 256, 0, stream>>>(wb4, ws4, wr);
    kan_fused<<<B, 256, 0, stream>>>(x, wb1, ws1, wb2, ws2, wb3, ws3, wr, fcw,
                                     fcb, out);
}

// Round 6
// 100.945 us; speedup vs baseline: 2.5639x; 2.5639x over previous
//
#include <hip/hip_runtime.h>

#define DEV __device__ __forceinline__

typedef _Float16 h2 __attribute__((ext_vector_type(2)));
typedef __fp16 f2 __attribute__((ext_vector_type(2)));

DEV unsigned h2bits(h2 h) { union { h2 h; unsigned u; } x; x.h = h; return x.u; }
DEV unsigned f2bits(f2 h) { union { f2 h; unsigned u; } x; x.h = h; return x.u; }
DEV h2 bits2h(unsigned u) { union { unsigned u; h2 h; } x; x.u = u; return x.h; }

// dot2: acc += a.x*b.x + a.y*b.y (f16 inputs, f32 accumulate, exact products)
#if __has_builtin(__builtin_amdgcn_fdot2)
DEV float dot2f(unsigned q, unsigned w, float acc) {
    return __builtin_amdgcn_fdot2(bits2h(q), bits2h(w), acc, false);
}
#else
DEV float dot2f(unsigned q, unsigned w, float acc) {
    h2 a = bits2h(q), b = bits2h(w);
    return fmaf((float)a.y, (float)b.y, fmaf((float)a.x, (float)b.x, acc));
}
#endif

// ---------------------------------------------------------------------------
// B-spline machinery: GRID_SIZE=5, DEGREE=3, knots t_i = (i-3)*0.4 - 1.
// Cox-de Boor exactly as the reference. All-unrolled, no runtime indexing.
// ---------------------------------------------------------------------------
DEV float silu_f(float v) { return v / (1.0f + __expf(-v)); }

DEV void bspline8(float x, float bb[8]) {
    float b[11];
#pragma unroll
    for (int i = 0; i < 11; ++i) {
        float g0 = (i - 3) * 0.4f - 1.0f;
        float g1 = (i - 2) * 0.4f - 1.0f;
        b[i] = ((x >= g0) && (x < g1)) ? 1.0f : 0.0f;
    }
#pragma unroll
    for (int d = 1; d <= 3; ++d) {
        const float inv = 1.0f / (0.4f * (float)d);
#pragma unroll
        for (int i = 0; i < 11 - d; ++i) {
            float gl = (i - 3) * 0.4f - 1.0f;
            float gr = (i - 3 + d + 1) * 0.4f - 1.0f;
            b[i] = (x - gl) * inv * b[i] + (gr - x) * inv * b[i + 1];
        }
    }
#pragma unroll
    for (int j = 0; j < 8; ++j) bb[j] = b[j];
}

// Even/odd-x column permutation: even x -> x/2, odd x -> W/2 + x/2.
// Makes the pooled conv's stride-2-x gathers stride-1 (conflict-free).
template <int W, bool PERM>
DEV int permcol(int x) {
    if (!PERM) return x;
    return (x & 1) ? (W / 2 + (x >> 1)) : (x >> 1);
}

// ---------------------------------------------------------------------------
// Expansion: silu (f32) + 8 bases packed as 4x f16-pairs (one uint4).
// Element NE is the zero-pad element: sil=0, bases=B(0).
// ---------------------------------------------------------------------------
template <int W, bool PERM>
DEV void expand_feat(const float* src, int NE, float* s_sil, uint4* s_bs, int tid) {
    for (int i = tid; i <= NE; i += 256) {
        float v = (i == NE) ? 0.0f : src[i];
        float bb[8];
        bspline8(v, bb);
        uint4 q;
        q.x = f2bits(__builtin_amdgcn_cvt_pkrtz(bb[0], bb[1]));
        q.y = f2bits(__builtin_amdgcn_cvt_pkrtz(bb[2], bb[3]));
        q.z = f2bits(__builtin_amdgcn_cvt_pkrtz(bb[4], bb[5]));
        q.w = f2bits(__builtin_amdgcn_cvt_pkrtz(bb[6], bb[7]));
        int widx = i;
        if (i < NE) {
            int y = i / W;
            int x = i - y * W;
            widx = y * W + permcol<W, PERM>(x);
        }
        s_sil[widx] = (i == NE) ? 0.0f : silu_f(v);
        s_bs[widx] = q;
    }
}

// ---------------------------------------------------------------------------
// Fused KANConv (k=3,pad=1) + 2x2/2 maxpool, pool done in registers.
// Each lane owns a 2x2 output patch for G channels. Weights: base f32 from
// global (wave-uniform -> s_load), spline packed f16x2 from global (same).
// ---------------------------------------------------------------------------
template <int CIN, int H, int W, int O, int G, bool PERM>
DEV void conv_pool_phase(const float* __restrict__ wb,
                         const unsigned* __restrict__ pw,
                         const float* s_sil, const uint4* s_bs, float* dst,
                         int tid) {
    constexpr int PH = H / 2;
    constexpr int HW2 = W / 2;
    constexpr int NPATCH = PH * PH;
    constexpr int NPIX = H * W;
    constexpr int NIN = CIN * NPIX;
    constexpr int F = CIN * 9;
    constexpr int NOG = O / G;
    static_assert(4 % NOG == 0, "waves must cover groups");

    const int wv = __builtin_amdgcn_readfirstlane(tid >> 6);
    const int ln = tid & 63;
    const int og = wv % NOG;            // uniform per wave
    const int poff = (wv / NOG) * 64;   // uniform per wave
    constexpr int PSTRIDE = 64 * (4 / NOG);

    for (int p = ln + poff; p < NPATCH; p += PSTRIDE) {
        const int py = p / PH, px = p - py * PH;
        int rowb[4], colb[4];
#pragma unroll
        for (int u = 0; u < 4; ++u) {
            int iy = 2 * py + u - 1;
            rowb[u] = ((unsigned)iy < (unsigned)H) ? iy * W : -0x40000000;
        }
#pragma unroll
        for (int v = 0; v < 4; ++v) {
            int ix = 2 * px + v - 1;
            int pc;
            if (PERM)
                pc = (v == 0) ? (HW2 + px - 1)
                              : (v == 1) ? px : (v == 2) ? (HW2 + px) : (px + 1);
            else
                pc = ix;
            colb[v] = ((unsigned)ix < (unsigned)W) ? pc : -0x40000000;
        }
        float acc[G][4];
#pragma unroll
        for (int g = 0; g < G; ++g)
#pragma unroll
            for (int q = 0; q < 4; ++q) acc[g][q] = 0.0f;

#pragma unroll 1
        for (int c = 0; c < CIN; ++c) {
#pragma unroll
            for (int u = 0; u < 4; ++u) {
#pragma unroll
                for (int v = 0; v < 4; ++v) {
                    const int raw = rowb[u] + colb[v];
                    const int idx = (raw < 0) ? NIN : c * NPIX + raw;
                    const float s = s_sil[idx];
                    const uint4 q = s_bs[idx];
#pragma unroll
                    for (int oy = 0; oy < 2; ++oy) {
                        const int dy = u - oy;
                        if (dy < 0 || dy > 2) continue;
#pragma unroll
                        for (int ox = 0; ox < 2; ++ox) {
                            const int dx = v - ox;
                            if (dx < 0 || dx > 2) continue;
                            const int ff = c * 9 + dy * 3 + dx;
#pragma unroll
                            for (int g = 0; g < G; ++g) {
                                const int o = og * G + g;            // uniform
                                const int wi = o * F + ff;           // uniform
                                float ag = acc[g][oy * 2 + ox];
                                ag = fmaf(wb[wi], s, ag);
                                ag = dot2f(q.x, pw[wi * 4 + 0], ag);
                                ag = dot2f(q.y, pw[wi * 4 + 1], ag);
                                ag = dot2f(q.z, pw[wi * 4 + 2], ag);
                                ag = dot2f(q.w, pw[wi * 4 + 3], ag);
                                acc[g][oy * 2 + ox] = ag;
                            }
                        }
                    }
                }
            }
        }
#pragma unroll
        for (int g = 0; g < G; ++g) {
            float m = fmaxf(fmaxf(acc[g][0], acc[g][1]), fmaxf(acc[g][2], acc[g][3]));
            dst[(og * G + g) * NPATCH + p] = m;
        }
    }
}

// ---------------------------------------------------------------------------
// Pixel-wise KANConv (odd 7x7 layer, no perm), writes conv output to s_out.
// ---------------------------------------------------------------------------
template <int CIN, int H, int W, int O, int G>
DEV void conv_phase(const float* __restrict__ wb, const unsigned* __restrict__ pw,
                    const float* s_sil, const uint4* s_bs, float* s_out, int tid) {
    constexpr int NPIX = H * W;
    constexpr int F = CIN * 9;
    constexpr int NOG = O / G;
    constexpr int NIN = CIN * NPIX;
    static_assert(4 % NOG == 0, "waves must cover groups");

    const int wv = __builtin_amdgcn_readfirstlane(tid >> 6);
    const int ln = tid & 63;
    const int og = wv % NOG;
    const int pxoff = (wv / NOG) * 64;
    constexpr int PXSTRIDE = 64 * (4 / NOG);

    for (int px = ln + pxoff; px < NPIX; px += PXSTRIDE) {
        const int y = px / W, x = px - y * W;
        int rowb[3], colb[3];
#pragma unroll
        for (int t = 0; t < 3; ++t) {
            int iy = y + t - 1;
            rowb[t] = ((unsigned)iy < (unsigned)H) ? iy * W : -0x40000000;
            int ix = x + t - 1;
            colb[t] = ((unsigned)ix < (unsigned)W) ? ix : -0x40000000;
        }
        float acc[G];
#pragma unroll
        for (int g = 0; g < G; ++g) acc[g] = 0.0f;

#pragma unroll 1
        for (int c = 0; c < CIN; ++c) {
#pragma unroll
            for (int ty = 0; ty < 3; ++ty) {
#pragma unroll
                for (int tx = 0; tx < 3; ++tx) {
                    const int raw = rowb[ty] + colb[tx];
                    const int idx = (raw < 0) ? NIN : c * NPIX + raw;
                    const float s = s_sil[idx];
                    const uint4 q = s_bs[idx];
                    const int ff = c * 9 + ty * 3 + tx;
#pragma unroll
                    for (int g = 0; g < G; ++g) {
                        const int o = og * G + g;
                        const int wi = o * F + ff;
                        float ag = acc[g];
                        ag = fmaf(wb[wi], s, ag);
                        ag = dot2f(q.x, pw[wi * 4 + 0], ag);
                        ag = dot2f(q.y, pw[wi * 4 + 1], ag);
                        ag = dot2f(q.z, pw[wi * 4 + 2], ag);
                        ag = dot2f(q.w, pw[wi * 4 + 3], ag);
                        acc[g] = ag;
                    }
                }
            }
        }
#pragma unroll
        for (int g = 0; g < G; ++g) s_out[(og * G + g) * NPIX + px] = acc[g];
    }
}

// ---------------------------------------------------------------------------
// Prep kernel (sample independent, 24 blocks, ~5us):
//  - wr layout: [0,512) Wb~[32][16]; [512,4608) Ws~[32][16][8]; [4608,4640) beta7
//  - pw1/pw2/pw3: spline weights packed as f16x2 pairs for layers 1..3
// d_ws float offsets: WR=0, PW1=4640 (144 u32), PW2=4784 (1152), PW3=5936 (4608)
// ---------------------------------------------------------------------------
__global__ __launch_bounds__(256) void kan_prep(
    const float* __restrict__ wb4, const float* __restrict__ ws4,
    const float* __restrict__ ws1, const float* __restrict__ ws2,
    const float* __restrict__ ws3, float* __restrict__ wsbase) {
    float* wr = wsbase;
    unsigned* pw1 = (unsigned*)(wsbase + 4640);
    unsigned* pw2 = (unsigned*)(wsbase + 4784);
    unsigned* pw3 = (unsigned*)(wsbase + 5936);
    const int bid = blockIdx.x;
    const int tid = threadIdx.x;

    if (bid == 0) {  // Wb~ [32][16]
        for (int i = tid; i < 512; i += 256) {
            int o = i / 16, c = i % 16;
            float s = 0.0f;
#pragma unroll
            for (int q = 0; q < 4; ++q) s += wb4[o * 64 + c * 4 + q];
            wr[i] = s;
        }
    } else if (bid == 1) {  // beta7[o] = 7 * sum_{f,j} ws4[o,f,j] * B_j(0)
        __shared__ float zb[8];
        if (tid == 0) {
            float zbb[8];
            bspline8(0.0f, zbb);
#pragma unroll
            for (int j = 0; j < 8; ++j) zb[j] = zbb[j];
        }
        __syncthreads();
        const int o = tid >> 3, j = tid & 7;  // 32 x 8
        float s = 0.0f;
        for (int f = 0; f < 64; ++f) s += ws4[(o * 64 + f) * 8 + j];
        s *= zb[j];
        s += __shfl_xor(s, 1);
        s += __shfl_xor(s, 2);
        s += __shfl_xor(s, 4);
        if (j == 0) wr[4608 + o] = 7.0f * s;
    } else if (bid < 18) {  // Ws~ [32][16][8] = 4096 over 16 blocks
        const int i = (bid - 2) * 256 + tid;
        int j = i % 8, c = (i / 8) % 16, o = i / 128;
        float s = 0.0f;
#pragma unroll
        for (int q = 0; q < 4; ++q) s += ws4[(o * 64 + c * 4 + q) * 8 + j];
        wr[512 + i] = s;
    } else {  // f16x2 packs: 144 + 1152 + 4608 = 5904 items over 6 blocks
        for (int i = (bid - 18) * 256 + tid; i < 5904; i += 6 * 256) {
            const float* src;
            unsigned* dst;
            int rel;
            if (i < 144) { src = ws1; dst = pw1; rel = i; }
            else if (i < 1296) { src = ws2; dst = pw2; rel = i - 144; }
            else { src = ws3; dst = pw3; rel = i - 1296; }
            int r = rel >> 2, t = rel & 3;
            h2 h;
            h.x = (_Float16)src[r * 8 + 2 * t];
            h.y = (_Float16)src[r * 8 + 2 * t + 1];
            dst[rel] = h2bits(h);
        }
    }
}

// ---------------------------------------------------------------------------
// Fully fused network: one block per sample, ~19.5 KB LDS.
// ---------------------------------------------------------------------------
__global__ __launch_bounds__(256, 6) void kan_fused(
    const float* __restrict__ x,
    const float* __restrict__ wb1, const float* __restrict__ wb2,
    const float* __restrict__ wb3, const float* __restrict__ wsbase,
    const float* __restrict__ fcw, const float* __restrict__ fcb,
    float* __restrict__ out) {
    const float* wr = wsbase;
    const unsigned* pw1 = (const unsigned*)(wsbase + 4640);
    const unsigned* pw2 = (const unsigned*)(wsbase + 4784);
    const unsigned* pw3 = (const unsigned*)(wsbase + 5936);

    __shared__ float s_sil[785];
    __shared__ uint4 s_bs[785];   // 8 f16 bases per element
    __shared__ float s_p[784];
    __shared__ float s_cs[144];
    __shared__ float s_pool[32];

    const int b = blockIdx.x;
    const int tid = threadIdx.x;

    for (int i = tid; i < 784; i += 256) s_p[i] = x[(size_t)b * 784 + i];
    __syncthreads();

    // ----- layer 1: [1,28,28] -> conv+pool -> [4,14,14] (in s_p)
    expand_feat<28, true>(s_p, 784, s_sil, s_bs, tid);
    __syncthreads();
    conv_pool_phase<1, 28, 28, 4, 2, true>(wb1, pw1, s_sil, s_bs, s_p, tid);
    __syncthreads();

    // ----- layer 2: [4,14,14] -> conv+pool -> [8,7,7] (in s_p)
    expand_feat<14, true>(s_p, 784, s_sil, s_bs, tid);
    __syncthreads();
    conv_pool_phase<4, 14, 14, 8, 2, true>(wb2, pw2, s_sil, s_bs, s_p, tid);
    __syncthreads();

    // ----- layer 3: [8,7,7] -> conv [16,7,7] (into s_p) -> pool [16,3,3] (s_cs)
    expand_feat<7, false>(s_p, 392, s_sil, s_bs, tid);
    __syncthreads();
    conv_phase<8, 7, 7, 16, 4>(wb3, pw3, s_sil, s_bs, s_p, tid);
    __syncthreads();
    for (int i = tid; i < 144; i += 256) {
        int o = i / 9;
        int r = i - o * 9;
        int py = r / 3, qx = r - py * 3;
        const float* src = &s_p[o * 49 + (2 * py) * 7 + 2 * qx];
        s_cs[i] = fmaxf(fmaxf(src[0], src[1]), fmaxf(src[7], src[8]));
    }
    __syncthreads();

    // ----- layer 4 + global-avg + fc (algebraically collapsed via wr)
    float* s_exp = (float*)s_bs;  // planar f32 scratch, needs 1296 of 3140
    if (tid < 144) {
        float v = s_cs[tid];
        float bb[8];
        bspline8(v, bb);
        s_exp[tid * 9 + 0] = silu_f(v);
#pragma unroll
        for (int j = 0; j < 8; ++j) s_exp[tid * 9 + 1 + j] = bb[j];
    }
    __syncthreads();
    if (tid < 144) {  // 16 channels x 9 components, summed over 9 pixels
        int c = tid / 9, comp = tid - (tid / 9) * 9;
        float s = 0.0f;
#pragma unroll
        for (int p = 0; p < 9; ++p) s += s_exp[(c * 9 + p) * 9 + comp];
        s_sil[tid] = s;  // channel-component sums
    }
    __syncthreads();
    if (tid < 32) {
        int o = tid;
        float acc = wr[4608 + o];  // 7 * sum(ws4 * B(0))
        for (int c = 0; c < 16; ++c) {
            acc += wr[o * 16 + c] * s_sil[c * 9 + 0];
#pragma unroll
            for (int j = 0; j < 8; ++j)
                acc += wr[512 + (o * 16 + c) * 8 + j] * s_sil[c * 9 + 1 + j];
        }
        s_pool[o] = acc * (1.0f / 16.0f);
    }
    __syncthreads();
    if (tid < 10) {
        float acc = fcb[tid];
#pragma unroll
        for (int c = 0; c < 32; ++c) acc += fcw[tid * 32 + c] * s_pool[c];
        out[(size_t)b * 10 + tid] = acc;
    }
}

// ---------------------------------------------------------------------------
extern "C" void kernel_launch(void* const* d_in, const int* in_sizes, int n_in,
                              void* d_out, int out_size, void* d_ws, size_t ws_size,
                              hipStream_t stream) {
    const float* x = (const float*)d_in[0];      // [B,1,28,28]
    const float* wb1 = (const float*)d_in[1];    // [4,9]
    const float* ws1 = (const float*)d_in[2];    // [4,9,8]
    const float* wb2 = (const float*)d_in[3];    // [8,36]
    const float* ws2 = (const float*)d_in[4];    // [8,36,8]
    const float* wb3 = (const float*)d_in[5];    // [16,72]
    const float* ws3 = (const float*)d_in[6];    // [16,72,8]
    const float* wb4 = (const float*)d_in[7];    // [32,64]
    const float* ws4 = (const float*)d_in[8];    // [32,64,8]
    const float* fcw = (const float*)d_in[9];    // [10,32]
    const float* fcb = (const float*)d_in[10];   // [10]
    float* out = (float*)d_out;

    const int B = in_sizes[0] / (28 * 28);
    float* wsbase = (float*)d_ws;  // 10544 floats used

    kan_prep<<<24, 256, 0, stream>>>(wb4, ws4, ws1, ws2, ws3, wsbase);
    kan_fused<<<B, 256, 0, stream>>>(x, wb1, wb2, wb3, wsbase, fcw, fcb, out);
}

// Round 8
// 56.724 us; speedup vs baseline: 4.5626x; 1.7796x over previous
//
#include <hip/hip_runtime.h>

#define DEV __device__ __forceinline__

typedef __fp16 h8 __attribute__((ext_vector_type(8)));
typedef float f32x4 __attribute__((ext_vector_type(4)));
union U4H { uint4 u; h8 h; };
union HS { _Float16 h; unsigned short s; };

DEV unsigned short h16(float x) { HS z; z.h = (_Float16)x; return z.s; }
DEV float silu_f(float v) { return v / (1.0f + __expf(-v)); }

// Cox-de Boor (reference-exact) — used only in prep/tail (cheap paths).
DEV void bspline8(float x, float bb[8]) {
    float b[11];
#pragma unroll
    for (int i = 0; i < 11; ++i) {
        float g0 = (i - 3) * 0.4f - 1.0f;
        float g1 = (i - 2) * 0.4f - 1.0f;
        b[i] = ((x >= g0) && (x < g1)) ? 1.0f : 0.0f;
    }
#pragma unroll
    for (int d = 1; d <= 3; ++d) {
        const float inv = 1.0f / (0.4f * (float)d);
#pragma unroll
        for (int i = 0; i < 11 - d; ++i) {
            float gl = (i - 3) * 0.4f - 1.0f;
            float gr = (i - 3 + d + 1) * 0.4f - 1.0f;
            b[i] = (x - gl) * inv * b[i] + (gr - x) * inv * b[i + 1];
        }
    }
#pragma unroll
    for (int j = 0; j < 8; ++j) bb[j] = b[j];
}

// ---------------------------------------------------------------------------
// Expansion: per input element one 32B record of 16 f16 components:
// comp0=sil_hi, comp1..8=B0..B7, comp9=sil_lo, comp10=sil_hi, comp11..15=0.
// Written into bordered planes (border = x=0 expansion: sil=0, bases=B(0)).
// Bases via closed-form cardinal cubic B-spline (uniform knots, h=0.4).
// ---------------------------------------------------------------------------
template <int CIN, int H, int W, int STRIDE>
DEV void expand(const float* src, char* planes, int tid) {
    constexpr int WC = W + 2, HC = H + 2;
    constexpr int CELLS = CIN * HC * WC;
    for (int cell = tid; cell < CELLS; cell += 256) {
        int c = cell / (HC * WC);
        int rr = cell - c * (HC * WC);
        int row = rr / WC, col = rr - row * WC;
        int y = row - 1, x = col - 1;
        bool inb = ((unsigned)y < (unsigned)H) && ((unsigned)x < (unsigned)W);
        float v = inb ? src[c * H * W + y * W + x] : 0.0f;
        float sil = silu_f(v);
        float shf = (float)(_Float16)sil;
        unsigned sh = h16(sil);
        unsigned slo = h16(sil - shf);
        char* rec = planes + (size_t)(c * (HC * STRIDE) + row * STRIDE + col) * 32;
        uint4 r0; r0.x = sh;          r0.y = 0u; r0.z = 0u; r0.w = 0u;
        uint4 r1; r1.x = (slo << 16); r1.y = sh; r1.z = 0u; r1.w = 0u;
        *(uint4*)rec = r0;
        *(uint4*)(rec + 16) = r1;
        float u = (v + 2.2f) * 2.5f;
        if (u >= 0.0f && u < 11.0f) {
            int mi = (int)u;
            float t = u - (float)mi;
            float t2 = t * t, t3 = t2 * t;
            float omt = 1.0f - t;
            float p3 = omt * omt * omt * (1.0f / 6.0f);
            float p2 = (3.0f * t3 - 6.0f * t2 + 4.0f) * (1.0f / 6.0f);
            float p1 = (-3.0f * t3 + 3.0f * t2 + 3.0f * t + 1.0f) * (1.0f / 6.0f);
            float p0 = t3 * (1.0f / 6.0f);
            int s0 = mi - 3;
            _Float16* bp = (_Float16*)(rec + 2);
            if (s0 >= 0) bp[s0] = (_Float16)p3;
            if (s0 >= -1 && s0 <= 6) bp[s0 + 1] = (_Float16)p2;
            if (s0 >= -2 && s0 <= 5) bp[s0 + 2] = (_Float16)p1;
            if (s0 <= 4) bp[s0 + 3] = (_Float16)p0;
        }
    }
}

// tap -> byte offset within planes (c = tap/9, dy = (tap%9)/3, dx = tap%3)
template <int H, int STRIDE>
DEV constexpr int tapoff(int t) {
    return ((t / 9) * ((H + 2) * STRIDE) + ((t % 9) / 3) * STRIDE + (t % 9) % 3) * 32;
}

// 2x2/2 maxpool of a 16x16 C-tile (rows = 2x8 positions, cols = channels)
template <int O, int PHV, int PWV>
DEV void poolwrite(f32x4 acc, int ty, int tx, int ln, float* s_next) {
    const int n = ln & 15, q = ln >> 4;
    float q0 = fmaxf(acc[0], acc[1]);
    float q1 = fmaxf(acc[2], acc[3]);
    float r0 = fmaxf(q0, __shfl_xor(q0, 32));
    float r1 = fmaxf(q1, __shfl_xor(q1, 32));
    if (ln < 32 && n < O && ty < PHV) {
        int ppx = tx * 4 + (q & 1) * 2;
        float* dst = s_next + n * (PHV * PWV) + ty * PWV + ppx;
        if (ppx < PWV) dst[0] = r0;
        if (ppx + 1 < PWV) dst[1] = r1;
    }
}

// ---------------------------------------------------------------------------
// One KANConv layer as MFMA GEMM: D[16 pos x 16 ch] += A[pos,k] * B[k,ch],
// k = tap*16 + comp. A-frag = 1 ds_read_b128/lane from planes; B-frag
// fragment-packed in global (prep kernel). Pool fused in registers.
// ---------------------------------------------------------------------------
template <int CIN, int H, int W, int O, int STRIDE, int NT, int KC, int BWC,
          int TX, int TPW, int PHV, int PWV>
DEV void layer_mfma(const uint4* __restrict__ pwB, const char* planes,
                    float* s_next, int tid) {
    const int wv = tid >> 6, ln = tid & 63;
    const int m = ln & 15;
    const int half = ln >> 4;
    const int tapsel = (half >> 1) & 1;
    const int bh = (half & 1) << 4;

    if constexpr (KC == BWC) {  // single chunk: B fully resident, acc per tile
        uint4 bw[BWC];
#pragma unroll
        for (int i = 0; i < BWC; ++i) bw[i] = pwB[i * 64 + ln];
#pragma unroll
        for (int tt = 0; tt < TPW; ++tt) {
            const int gid = wv * TPW + tt;
            const int ty = gid / TX, tx = gid - ty * TX;
            const int py = min(2 * ty + (m >> 3), H - 1);
            const int px = min(tx * 8 + (m & 7), W - 1);
            const int base = (py * STRIDE + px) * 32 + bh;
            f32x4 acc = {0.f, 0.f, 0.f, 0.f};
#pragma unroll
            for (int i = 0; i < BWC; ++i) {
                const int t0 = min(2 * i, NT - 1), t1 = min(2 * i + 1, NT - 1);
                const int off = tapsel ? tapoff<H, STRIDE>(t1) : tapoff<H, STRIDE>(t0);
                U4H a; a.u = *(const uint4*)(planes + base + off);
                U4H b; b.u = bw[i];
                acc = __builtin_amdgcn_mfma_f32_16x16x32_f16(a.h, b.h, acc, 0, 0, 0);
            }
            poolwrite<O, PHV, PWV>(acc, ty, tx, ln, s_next);
        }
    } else {  // chunked B, all tiles' acc resident
        f32x4 acc[TPW];
        int base[TPW], tyA[TPW], txA[TPW];
#pragma unroll
        for (int tt = 0; tt < TPW; ++tt) {
            acc[tt] = {0.f, 0.f, 0.f, 0.f};
            const int gid = wv * TPW + tt;
            tyA[tt] = gid / TX;
            txA[tt] = gid - tyA[tt] * TX;
            const int py = min(2 * tyA[tt] + (m >> 3), H - 1);
            const int px = min(txA[tt] * 8 + (m & 7), W - 1);
            base[tt] = (py * STRIDE + px) * 32 + bh;
        }
#pragma unroll
        for (int kc = 0; kc < KC; kc += BWC) {
            uint4 bw[BWC];
#pragma unroll
            for (int i = 0; i < BWC; ++i) bw[i] = pwB[(kc + i) * 64 + ln];
#pragma unroll
            for (int i = 0; i < BWC; ++i) {
                const int kf = kc + i;
                const int t0 = min(2 * kf, NT - 1), t1 = min(2 * kf + 1, NT - 1);
                const int off = tapsel ? tapoff<H, STRIDE>(t1) : tapoff<H, STRIDE>(t0);
#pragma unroll
                for (int tt = 0; tt < TPW; ++tt) {
                    U4H a; a.u = *(const uint4*)(planes + base[tt] + off);
                    U4H b; b.u = bw[i];
                    acc[tt] = __builtin_amdgcn_mfma_f32_16x16x32_f16(a.h, b.h, acc[tt], 0, 0, 0);
                }
            }
        }
#pragma unroll
        for (int tt = 0; tt < TPW; ++tt)
            poolwrite<O, PHV, PWV>(acc[tt], tyA[tt], txA[tt], ln, s_next);
    }
}

// ---------------------------------------------------------------------------
// Prep: wr (collapsed layer-4 weights) + fragment-packed B for layers 1..3.
// w(n,k): comp0=w_hi(base), 1..8=ws, 9=w_hi, 10=w_lo, else 0.
// d_ws f32 offsets: wr[0,4640); pwB1@4640 (1280 u32); pwB2@5920 (4608);
// pwB3@10528 (9216).
// ---------------------------------------------------------------------------
DEV float wval(const float* wb, const float* ws, int NT, int O, int n, int k) {
    int tap = k >> 4, comp = k & 15;
    if (n >= O || tap >= NT) return 0.f;
    if (comp >= 1 && comp <= 8) return ws[(n * NT + tap) * 8 + comp - 1];
    if (comp > 10) return 0.f;
    float w = wb[n * NT + tap];
    float hi = (float)(_Float16)w;
    return (comp == 10) ? (w - hi) : hi;
}

DEV unsigned packw(float a, float b) {
    return (unsigned)h16(a) | ((unsigned)h16(b) << 16);
}

__global__ __launch_bounds__(256) void kan_prep(
    const float* __restrict__ wb1, const float* __restrict__ ws1,
    const float* __restrict__ wb2, const float* __restrict__ ws2,
    const float* __restrict__ wb3, const float* __restrict__ ws3,
    const float* __restrict__ wb4, const float* __restrict__ ws4,
    float* __restrict__ wsbase) {
    float* wr = wsbase;
    const int bid = blockIdx.x;
    const int tid = threadIdx.x;

    if (bid == 0) {  // Wb~ [32][16]
        for (int i = tid; i < 512; i += 256) {
            int o = i / 16, c = i % 16;
            float s = 0.0f;
#pragma unroll
            for (int q = 0; q < 4; ++q) s += wb4[o * 64 + c * 4 + q];
            wr[i] = s;
        }
    } else if (bid == 1) {  // beta7[o] = 7 * sum_{f,j} ws4[o,f,j] * B_j(0)
        __shared__ float zb[8];
        if (tid == 0) {
            float zbb[8];
            bspline8(0.0f, zbb);
#pragma unroll
            for (int j = 0; j < 8; ++j) zb[j] = zbb[j];
        }
        __syncthreads();
        const int o = tid >> 3, j = tid & 7;
        float s = 0.0f;
        for (int f = 0; f < 64; ++f) s += ws4[(o * 64 + f) * 8 + j];
        s *= zb[j];
        s += __shfl_xor(s, 1);
        s += __shfl_xor(s, 2);
        s += __shfl_xor(s, 4);
        if (j == 0) wr[4608 + o] = 7.0f * s;
    } else if (bid < 18) {  // Ws~ [32][16][8]
        const int i = (bid - 2) * 256 + tid;
        int j = i % 8, c = (i / 8) % 16, o = i / 128;
        float s = 0.0f;
#pragma unroll
        for (int q = 0; q < 4; ++q) s += ws4[(o * 64 + c * 4 + q) * 8 + j];
        wr[512 + i] = s;
    } else {  // pwB packing: 1280 + 4608 + 9216 = 15104 u32 items
        int g = (bid - 18) * 256 + tid;
        if (g < 15104) {
            const float *wb, *ws;
            unsigned* dst;
            int NT, O, rel;
            if (g < 1280) {
                wb = wb1; ws = ws1; NT = 9; O = 4; rel = g;
                dst = (unsigned*)(wsbase + 4640);
            } else if (g < 5888) {
                wb = wb2; ws = ws2; NT = 36; O = 8; rel = g - 1280;
                dst = (unsigned*)(wsbase + 5920);
            } else {
                wb = wb3; ws = ws3; NT = 72; O = 16; rel = g - 5888;
                dst = (unsigned*)(wsbase + 10528);
            }
            int kf = rel >> 8;
            int lane = (rel >> 2) & 63;
            int j = rel & 3;
            int k0 = kf * 32 + ((lane >> 4) & 3) * 8 + j * 2;
            int n = lane & 15;
            dst[rel] = packw(wval(wb, ws, NT, O, n, k0),
                             wval(wb, ws, NT, O, n, k0 + 1));
        }
    }
}

// ---------------------------------------------------------------------------
// Fused network, one block (4 waves) per sample. Planes region 34816 B.
// ---------------------------------------------------------------------------
__global__ __launch_bounds__(256, 4) void kan_fused(
    const float* __restrict__ x, const float* __restrict__ wsbase,
    const float* __restrict__ fcw, const float* __restrict__ fcb,
    float* __restrict__ out) {
    __shared__ uint4 s_planes4[2176];  // 34816 B
    __shared__ float s_next[784];
    __shared__ float s_sum[144];
    __shared__ float s_pool[32];
    char* planes = (char*)s_planes4;

    const int b = blockIdx.x;
    const int tid = threadIdx.x;
    const float* wr = wsbase;
    const uint4* pw1 = (const uint4*)(wsbase + 4640);
    const uint4* pw2 = (const uint4*)(wsbase + 5920);
    const uint4* pw3 = (const uint4*)(wsbase + 10528);

    // ----- layer 1: [1,28,28] -> [4,14,14]
    expand<1, 28, 28, 31>(x + (size_t)b * 784, planes, tid);
    __syncthreads();
    layer_mfma<1, 28, 28, 4, 31, 9, 5, 5, 4, 14, 14, 14>(pw1, planes, s_next, tid);
    __syncthreads();

    // ----- layer 2: [4,14,14] -> [8,7,7]
    expand<4, 14, 14, 17>(s_next, planes, tid);
    __syncthreads();
    layer_mfma<4, 14, 14, 8, 17, 36, 18, 9, 2, 4, 7, 7>(pw2, planes, s_next, tid);
    __syncthreads();

    // ----- layer 3: [8,7,7] -> [16,3,3]
    expand<8, 7, 7, 9>(s_next, planes, tid);
    __syncthreads();
    layer_mfma<8, 7, 7, 16, 9, 72, 36, 9, 1, 1, 3, 3>(pw3, planes, s_next, tid);
    __syncthreads();

    // ----- layer 4 + global-avg + fc (collapsed via wr), s_next = [16][3][3]
    float* s_exp = (float*)s_planes4;  // 1296 f32 scratch
    if (tid < 144) {
        float v = s_next[tid];
        float bb[8];
        bspline8(v, bb);
        s_exp[tid * 9 + 0] = silu_f(v);
#pragma unroll
        for (int j = 0; j < 8; ++j) s_exp[tid * 9 + 1 + j] = bb[j];
    }
    __syncthreads();
    if (tid < 144) {
        int c = tid / 9, comp = tid - (tid / 9) * 9;
        float s = 0.0f;
#pragma unroll
        for (int p = 0; p < 9; ++p) s += s_exp[(c * 9 + p) * 9 + comp];
        s_sum[tid] = s;
    }
    __syncthreads();
    if (tid < 32) {
        int o = tid;
        float acc = wr[4608 + o];
        for (int c = 0; c < 16; ++c) {
            acc += wr[o * 16 + c] * s_sum[c * 9 + 0];
#pragma unroll
            for (int j = 0; j < 8; ++j)
                acc += wr[512 + (o * 16 + c) * 8 + j] * s_sum[c * 9 + 1 + j];
        }
        s_pool[o] = acc * (1.0f / 16.0f);
    }
    __syncthreads();
    if (tid < 10) {
        float acc = fcb[tid];
#pragma unroll
        for (int c = 0; c < 32; ++c) acc += fcw[tid * 32 + c] * s_pool[c];
        out[(size_t)b * 10 + tid] = acc;
    }
}

// ---------------------------------------------------------------------------
extern "C" void kernel_launch(void* const* d_in, const int* in_sizes, int n_in,
                              void* d_out, int out_size, void* d_ws, size_t ws_size,
                              hipStream_t stream) {
    const float* x = (const float*)d_in[0];      // [B,1,28,28]
    const float* wb1 = (const float*)d_in[1];    // [4,9]
    const float* ws1 = (const float*)d_in[2];    // [4,9,8]
    const float* wb2 = (const float*)d_in[3];    // [8,36]
    const float* ws2 = (const float*)d_in[4];    // [8,36,8]
    const float* wb3 = (const float*)d_in[5];    // [16,72]
    const float* ws3 = (const float*)d_in[6];    // [16,72,8]
    const float* wb4 = (const float*)d_in[7];    // [32,64]
    const float* ws4 = (const float*)d_in[8];    // [32,64,8]
    const float* fcw = (const float*)d_in[9];    // [10,32]
    const float* fcb = (const float*)d_in[10];   // [10]
    float* out = (float*)d_out;

    const int B = in_sizes[0] / (28 * 28);
    float* wsbase = (float*)d_ws;  // 19744 floats used

    kan_prep<<<77, 256, 0, stream>>>(wb1, ws1, wb2, ws2, wb3, ws3, wb4, ws4,
                                     wsbase);
    kan_fused<<<B, 256, 0, stream>>>(x, wsbase, fcw, fcb, out);
}